// Round 10
// baseline (73.943 us; speedup 1.0000x reference)
//
#include <hip/hip_runtime.h>

// Problem constants (from the reference):
//   B=32768 batch, T=256 trees, D=10 depth, F=512 features, C=1 leaf dim
constexpr int kB = 32768;
constexpr int kT = 256;
constexpr int kD = 10;
constexpr int kF = 512;
constexpr int kLvlPad = kT << (kD - 1); // 131072

constexpr int kRows    = 16;             // batch rows per block
constexpr int kTrees   = 128;            // trees per block (4 chains/thread)
constexpr int kChains  = 4;
constexpr int kThreads = 512;
constexpr int kXPad    = 516;            // padded x row stride (floats)
constexpr int kOPad    = kTrees + 1;     // outs stride 129

// Table layout in d_ws (units of 16B int4 records):
//  P01[t]   : 256 recs  — {root|n1L<<9|n1R<<18, b_root, b1L, b1R}; p_out=4t+2c0+c1
//  P23[p]   : 1024 recs — levels (2,3): {n2|n3L<<9|n3R<<18, b2, b3L, b3R}
//  P45[p]   : 4096 recs — levels (4,5)
//  P67[p]   : 16384 recs— levels (6,7)
//  F89[p]   : 65536 recs x 32B — {n8|n9L<<9|n9R<<18, b8, b9L, b9R, leaf[4]}
//             both 16B halves share a cache line and load in parallel.
constexpr int kN01 = 256;
constexpr int kN23 = 1024;
constexpr int kN45 = 4096;
constexpr int kN67 = 16384;
constexpr int kNF  = 65536;
constexpr int kO01 = 0;
constexpr int kO23 = kO01 + kN01;  // 256
constexpr int kO45 = kO23 + kN23;  // 1280
constexpr int kO67 = kO45 + kN45;  // 5376
constexpr int kOFU = kO67 + kN67;  // 21760  (F89 occupies 2 recs each)
constexpr int kPairTotal = kOFU;               // 21760 pair records
constexpr int kPrepThreads = kPairTotal + kNF; // 87296
constexpr size_t kWsBytes = (size_t)(kOFU + 2 * kNF) * 16; // 2,445,312 B

// Build all tables in one launch.
__global__ __launch_bounds__(256)
void prep_kernel(const int* __restrict__ root_nodes,
                 const float* __restrict__ root_biases,
                 const int* __restrict__ nodes, const float* __restrict__ biases,
                 const float* __restrict__ leaf_nodes, int4* __restrict__ ws)
{
    int idx = blockIdx.x * 256 + threadIdx.x;
    if (idx < kPairTotal) {
        // Pair tables. Top level L uses arrays nodes[L-1] (L=0 -> roots),
        // child level L+1 uses nodes[L].
        int j, topL;
        if      (idx < kO23) { topL = 0; j = idx - kO01; }
        else if (idx < kO45) { topL = 2; j = idx - kO23; }
        else if (idx < kO67) { topL = 4; j = idx - kO45; }
        else                 { topL = 6; j = idx - kO67; }
        int   nt; float bt;
        if (topL == 0) { nt = root_nodes[j]; bt = root_biases[j]; }
        else {
            nt = nodes [(size_t)(topL - 1) * kLvlPad + j];
            bt = biases[(size_t)(topL - 1) * kLvlPad + j];
        }
        const int*   nc = nodes  + (size_t)topL * kLvlPad; // child row (level topL+1)
        const float* bc = biases + (size_t)topL * kLvlPad;
        unsigned int pk = (unsigned int)nt
                        | ((unsigned int)nc[2 * j]     << 9)
                        | ((unsigned int)nc[2 * j + 1] << 18);
        ws[idx] = make_int4((int)pk, __float_as_int(bt),
                            __float_as_int(bc[2 * j]),
                            __float_as_int(bc[2 * j + 1]));
    } else if (idx < kPrepThreads) {
        int j = idx - kPairTotal;     // level-8 global index, [0, 65536)
        const int   n8 = nodes [(size_t)7 * kLvlPad + j];
        const float b8 = biases[(size_t)7 * kLvlPad + j];
        const int*   n9 = nodes  + (size_t)8 * kLvlPad;
        const float* b9 = biases + (size_t)8 * kLvlPad;
        unsigned int pk = (unsigned int)n8
                        | ((unsigned int)n9[2 * j]     << 9)
                        | ((unsigned int)n9[2 * j + 1] << 18);
        ws[kOFU + 2 * j] = make_int4((int)pk, __float_as_int(b8),
                                     __float_as_int(b9[2 * j]),
                                     __float_as_int(b9[2 * j + 1]));
        ws[kOFU + 2 * j + 1] =
            make_int4(__float_as_int(leaf_nodes[4 * j]),
                      __float_as_int(leaf_nodes[4 * j + 1]),
                      __float_as_int(leaf_nodes[4 * j + 2]),
                      __float_as_int(leaf_nodes[4 * j + 3]));
    }
}

// Block = 16 batch rows x 128 trees, 512 threads, 4 independent chains per
// thread. Wave lanes: lane&15 = row -> 16 lanes share each tree (shallow
// gathers coalesce; shallow LDS reads are 2-way/bank = free). Chain:
// P01 -> P23 -> P45 -> P67 -> F89(lo||hi) = 5 serial gathers (root and leaf
// folded into tables). xs reused as output staging. Grid swizzled so the 2
// tree-tiles of one x-tile sit 8 dispatch slots apart (same XCD).
__global__ __launch_bounds__(kThreads)
void traverse_pair_kernel(const float* __restrict__ x,
                          const int4* __restrict__ ws,
                          float* __restrict__ out)
{
    __shared__ float xs[kRows][kXPad];        // 33,024 B (reused for outs)
    float* outs = &xs[0][0];                  // alias: [kRows][kOPad]

    const int bid = blockIdx.x;
    const int w   = bid >> 4;        // 16-block window
    const int s   = bid & 15;
    const int bx  = w * 8 + (s & 7); // x-tile, [0, 2048)
    const int by  = s >> 3;          // tree tile, [0, 2)
    const int b0  = bx * kRows;
    const int t0  = by * kTrees;
    const int tid = threadIdx.x;

    // Stage 16 x rows (2048 float4), coalesced.
    {
        const float4* xg = reinterpret_cast<const float4*>(x + (size_t)b0 * kF);
#pragma unroll
        for (int k = 0; k < 4; ++k) {
            int j = tid + k * kThreads;   // 0..2047
            int r = j >> 7;
            int c = j & 127;
            float4 v = xg[(size_t)r * (kF / 4) + c];
            *reinterpret_cast<float4*>(&xs[r][c * 4]) = v;
        }
    }
    __syncthreads();

    const int r  = tid & (kRows - 1); // row within tile
    const int tt = tid >> 4;          // 0..31
    const float* __restrict__ xrow = xs[r];

    const int4* __restrict__ P01 = ws + kO01;
    const int4* __restrict__ P23 = ws + kO23;
    const int4* __restrict__ P45 = ws + kO45;
    const int4* __restrict__ P67 = ws + kO67;
    const int4* __restrict__ FU  = ws + kOFU;

    int p[kChains];
#pragma unroll
    for (int c = 0; c < kChains; ++c)
        p[c] = t0 + tt + 32 * c;      // index into P01

    // One pair step: one 16B gather advances two levels.
    // c0=1 -> right child (reference: prev = 2*prev + cond).
#define PAIR_STEP(TBL)                                                        \
    {                                                                         \
        int4 rec[kChains];                                                    \
        _Pragma("unroll")                                                     \
        for (int c = 0; c < kChains; ++c) rec[c] = TBL[p[c]];                 \
        _Pragma("unroll")                                                     \
        for (int c = 0; c < kChains; ++c) {                                   \
            unsigned int n = (unsigned int)rec[c].x;                          \
            int c0 = xrow[n & 511u] <= __int_as_float(rec[c].y) ? 1 : 0;      \
            int nc = c0 ? (int)((n >> 18) & 511u) : (int)((n >> 9) & 511u);   \
            int bb = c0 ? rec[c].w : rec[c].z;                                \
            int c1 = xrow[nc] <= __int_as_float(bb) ? 1 : 0;                  \
            p[c] = 4 * p[c] + 2 * c0 + c1;                                    \
        }                                                                     \
    }

    PAIR_STEP(P01)  // root + level 1   -> p in [0, 1024)
    PAIR_STEP(P23)  // levels 2,3       -> p in [0, 4096)
    PAIR_STEP(P45)  // levels 4,5       -> p in [0, 16384)
    PAIR_STEP(P67)  // levels 6,7       -> p in [0, 65536)
#undef PAIR_STEP

    // Triple-fused tail: levels 8,9 + leaf from one 32B record.
    float leaf[kChains];
    {
        int4 lo[kChains], hi[kChains];
#pragma unroll
        for (int c = 0; c < kChains; ++c) {
            lo[c] = FU[2 * p[c]];
            hi[c] = FU[2 * p[c] + 1];   // same cache line, parallel issue
        }
#pragma unroll
        for (int c = 0; c < kChains; ++c) {
            unsigned int n = (unsigned int)lo[c].x;
            int c8 = xrow[n & 511u] <= __int_as_float(lo[c].y) ? 1 : 0;
            int n9 = c8 ? (int)((n >> 18) & 511u) : (int)((n >> 9) & 511u);
            int b9 = c8 ? lo[c].w : lo[c].z;
            int c9 = xrow[n9] <= __int_as_float(b9) ? 1 : 0;
            // leaf index 2*c8 + c9, selected without dynamic indexing:
            int lv = c8 ? (c9 ? hi[c].w : hi[c].z)
                        : (c9 ? hi[c].y : hi[c].x);
            leaf[c] = __int_as_float(lv);
        }
    }

    // xs is dead now; reuse it as the output staging buffer.
    __syncthreads();
#pragma unroll
    for (int c = 0; c < kChains; ++c)
        outs[r * kOPad + tt + 32 * c] = leaf[c];
    __syncthreads();

#pragma unroll
    for (int k = 0; k < 4; ++k) {
        int j    = tid + k * kThreads;  // 0..2047
        int orow = j >> 7;              // 0..15
        int ocol = j & 127;             // 0..127
        __builtin_nontemporal_store(outs[orow * kOPad + ocol],
                                    &out[(size_t)(b0 + orow) * kT + t0 + ocol]);
    }
}

// Fallback (no workspace): straightforward per-level walk.
__global__ __launch_bounds__(512)
void traverse_plain_kernel(const float* __restrict__ x,
                           const int* __restrict__ root_nodes,
                           const float* __restrict__ root_biases,
                           const int* __restrict__ nodes,
                           const float* __restrict__ biases,
                           const float* __restrict__ leaf_nodes,
                           float* __restrict__ out)
{
    __shared__ float xs[16][kXPad];
    __shared__ float outs[16][65];

    const int b0  = blockIdx.x * 16;
    const int t0  = blockIdx.y * 64;
    const int tid = threadIdx.x;

    {
        const float4* xg = reinterpret_cast<const float4*>(x + (size_t)b0 * kF);
#pragma unroll
        for (int k = 0; k < 4; ++k) {
            int j = tid + k * 512;
            int r = j >> 7;
            int c = j & 127;
            float4 v = xg[(size_t)r * (kF / 4) + c];
            *reinterpret_cast<float4*>(&xs[r][c * 4]) = v;
        }
    }
    __syncthreads();

    const int r  = tid & 15;
    const int tt = tid >> 4;
    const int tA = t0 + tt;
    const int tB = t0 + tt + 32;
    const float* __restrict__ xrow = xs[r];

    int pA = 2 * tA + (xrow[root_nodes[tA]] <= root_biases[tA] ? 1 : 0);
    int pB = 2 * tB + (xrow[root_nodes[tB]] <= root_biases[tB] ? 1 : 0);

#pragma unroll
    for (int i = 1; i < kD; ++i) {
        const int*   ln = nodes  + (size_t)(i - 1) * kLvlPad;
        const float* lb = biases + (size_t)(i - 1) * kLvlPad;
        int   nA = ln[pA], nB = ln[pB];
        float bA = lb[pA], bB = lb[pB];
        pA = 2 * pA + (xrow[nA] <= bA ? 1 : 0);
        pB = 2 * pB + (xrow[nB] <= bB ? 1 : 0);
    }

    outs[r][tt]      = leaf_nodes[pA];
    outs[r][tt + 32] = leaf_nodes[pB];
    __syncthreads();

#pragma unroll
    for (int k = 0; k < 2; ++k) {
        int j    = tid + k * 512;
        int orow = j >> 6;
        int ocol = j & 63;
        __builtin_nontemporal_store(outs[orow][ocol],
                                    &out[(size_t)(b0 + orow) * kT + t0 + ocol]);
    }
}

extern "C" void kernel_launch(void* const* d_in, const int* in_sizes, int n_in,
                              void* d_out, int out_size, void* d_ws, size_t ws_size,
                              hipStream_t stream) {
    const float* x           = (const float*)d_in[0];
    const int*   root_nodes  = (const int*)d_in[1];
    const float* root_biases = (const float*)d_in[2];
    const int*   nodes       = (const int*)d_in[3];
    const float* biases      = (const float*)d_in[4];
    const float* leaf_nodes  = (const float*)d_in[5];
    float*       out         = (float*)d_out;

    if (ws_size >= kWsBytes) {
        prep_kernel<<<(kPrepThreads + 255) / 256, 256, 0, stream>>>(
            root_nodes, root_biases, nodes, biases, leaf_nodes, (int4*)d_ws);
        const int nblocks = (kB / kRows) * (kT / kTrees); // 2048 * 2 = 4096
        traverse_pair_kernel<<<nblocks, kThreads, 0, stream>>>(
            x, (const int4*)d_ws, out);
    } else {
        dim3 grid(kB / 16, kT / 64); // (2048, 4)
        traverse_plain_kernel<<<grid, 512, 0, stream>>>(
            x, root_nodes, root_biases, nodes, biases, leaf_nodes, out);
    }
}

// Round 11
// 67.378 us; speedup vs baseline: 1.0974x; 1.0974x over previous
//
#include <hip/hip_runtime.h>

// Problem constants (from the reference):
//   B=32768 batch, T=256 trees, D=10 depth, F=512 features, C=1 leaf dim
constexpr int kB = 32768;
constexpr int kT = 256;
constexpr int kD = 10;
constexpr int kF = 512;
constexpr int kLvlPad = kT << (kD - 1); // 131072
constexpr int kLevels = kD - 1;         // 9

constexpr int kRows    = 16;             // batch rows per block
constexpr int kTrees   = 128;            // trees per block (4 chains per thread)
constexpr int kChains  = 4;
constexpr int kThreads = 512;
constexpr int kXPad    = 516;            // padded x row stride (floats)
constexpr int kOPad    = kTrees + 1;     // outs stride 129

// Pair-table record counts / offsets (16B records in d_ws).
// Pair (i,i+1) table indexed by the GLOBAL level-i index (width T*2^i):
//   {u32 n_top|nL<<9|nR<<18, f32 b_top, f32 bL, f32 bR}  (node idx < 512)
// One dwordx4 gather advances TWO levels. Fused record (level 9 + leaf):
//   {n9, b9, leaf[2j], leaf[2j+1]} indexed by global level-9 index.
constexpr int kP1 = kT * 2;      // 512
constexpr int kP3 = kT * 8;      // 2048
constexpr int kP5 = kT * 32;     // 8192
constexpr int kP7 = kT * 128;    // 32768
constexpr int kFU = kT * 512;    // 131072
constexpr int kO1 = 0;
constexpr int kO3 = kO1 + kP1;   // 512
constexpr int kO5 = kO3 + kP3;   // 2560
constexpr int kO7 = kO5 + kP5;   // 10752
constexpr int kOF = kO7 + kP7;   // 43520
constexpr int kTotalRecs = kOF + kFU; // 174592
constexpr size_t kWsBytes = (size_t)kTotalRecs * 16; // 2,793,472 B

// Build all pair tables + fused table in one launch.
__global__ __launch_bounds__(256)
void prep_kernel(const int* __restrict__ nodes, const float* __restrict__ biases,
                 const float* __restrict__ leaf_nodes, int4* __restrict__ ws)
{
    int idx = blockIdx.x * 256 + threadIdx.x;
    if (idx < kOF) {
        int i, base;
        if      (idx < kO3) { i = 1; base = kO1; }
        else if (idx < kO5) { i = 3; base = kO3; }
        else if (idx < kO7) { i = 5; base = kO5; }
        else                { i = 7; base = kO7; }
        int j = idx - base;                      // global index into level i
        const int*   nt = nodes  + (size_t)(i - 1) * kLvlPad; // level i
        const float* bt = biases + (size_t)(i - 1) * kLvlPad;
        const int*   nc = nodes  + (size_t)i * kLvlPad;       // level i+1
        const float* bc = biases + (size_t)i * kLvlPad;
        unsigned int pk = (unsigned int)nt[j]
                        | ((unsigned int)nc[2 * j]     << 9)
                        | ((unsigned int)nc[2 * j + 1] << 18);
        ws[idx] = make_int4((int)pk, __float_as_int(bt[j]),
                            __float_as_int(bc[2 * j]),
                            __float_as_int(bc[2 * j + 1]));
    } else if (idx < kTotalRecs) {
        int j = idx - kOF;                       // global index into level 9
        const int   n9 = nodes [(size_t)(kD - 2) * kLvlPad + j];
        const float b9 = biases[(size_t)(kD - 2) * kLvlPad + j];
        ws[idx] = make_int4(n9, __float_as_int(b9),
                            __float_as_int(leaf_nodes[2 * j]),
                            __float_as_int(leaf_nodes[2 * j + 1]));
    }
}

// EXACT round-8 structure (67.4us best): block = 16 batch rows x 128 trees,
// 512 threads, 4 independent chains per thread. Wave lanes: lane&15 = row ->
// 16 lanes share each tree so shallow pair gathers coalesce. Chain: root ->
// 4 pair-steps -> fused = 6 dependent gathers. xs reused as output staging.
// Grid swizzled so the 2 tree-tiles of an x-tile sit 8 dispatch slots apart
// (same XCD).
// SINGLE CHANGE vs R8: pair steps speculatively read top + BOTH child
// features from LDS in parallel (one lgkm round-trip instead of two serial),
// selecting after the compare. Cuts ~1 LDS round-trip from each of the 4
// pair steps on the exposed serial chain.
__global__ __launch_bounds__(kThreads)
void traverse_pair_kernel(const float* __restrict__ x,
                          const int* __restrict__ root_nodes,
                          const float* __restrict__ root_biases,
                          const int4* __restrict__ ws,
                          float* __restrict__ out)
{
    __shared__ float xs[kRows][kXPad];        // 33,024 B (reused for outs)
    float* outs = &xs[0][0];                  // alias: [kRows][kOPad]

    const int bid = blockIdx.x;
    const int w   = bid >> 4;        // 16-block window
    const int s   = bid & 15;
    const int bx  = w * 8 + (s & 7); // x-tile, [0, 2048)
    const int by  = s >> 3;          // tree tile, [0, 2)
    const int b0  = bx * kRows;
    const int t0  = by * kTrees;
    const int tid = threadIdx.x;

    // Stage 16 x rows (2048 float4), coalesced.
    {
        const float4* xg = reinterpret_cast<const float4*>(x + (size_t)b0 * kF);
#pragma unroll
        for (int k = 0; k < 4; ++k) {
            int j = tid + k * kThreads;   // 0..2047
            int r = j >> 7;
            int c = j & 127;
            float4 v = xg[(size_t)r * (kF / 4) + c];
            *reinterpret_cast<float4*>(&xs[r][c * 4]) = v;
        }
    }
    __syncthreads();

    const int r  = tid & (kRows - 1); // row within tile
    const int tt = tid >> 4;          // 0..31
    const float* __restrict__ xrow = xs[r];

    int p[kChains];
#pragma unroll
    for (int c = 0; c < kChains; ++c) {
        int t = t0 + tt + 32 * c;
        p[c] = 2 * t + (xrow[root_nodes[t]] <= root_biases[t] ? 1 : 0);
    }

    const int4* __restrict__ P1 = ws + kO1;
    const int4* __restrict__ P3 = ws + kO3;
    const int4* __restrict__ P5 = ws + kO5;
    const int4* __restrict__ P7 = ws + kO7;
    const int4* __restrict__ FU = ws + kOF;

    // Pair step: one 16B gather advances two levels. Speculative parallel
    // LDS reads of top + both child features (one wait instead of two).
#define PAIR_STEP(TBL)                                                        \
    {                                                                         \
        int4 rec[kChains];                                                    \
        _Pragma("unroll")                                                     \
        for (int c = 0; c < kChains; ++c) rec[c] = TBL[p[c]];                 \
        _Pragma("unroll")                                                     \
        for (int c = 0; c < kChains; ++c) {                                   \
            unsigned int n = (unsigned int)rec[c].x;                          \
            float ft = xrow[n & 511u];                                        \
            float fl = xrow[(n >> 9) & 511u];                                 \
            float fr = xrow[(n >> 18) & 511u];                                \
            int c0 = ft <= __int_as_float(rec[c].y) ? 1 : 0;                  \
            float fc = c0 ? fr : fl;                                          \
            int   bb = c0 ? rec[c].w : rec[c].z;                              \
            int c1 = fc <= __int_as_float(bb) ? 1 : 0;                        \
            p[c] = 4 * p[c] + 2 * c0 + c1;                                    \
        }                                                                     \
    }

    PAIR_STEP(P1)   // levels 1,2
    PAIR_STEP(P3)   // levels 3,4
    PAIR_STEP(P5)   // levels 5,6
    PAIR_STEP(P7)   // levels 7,8
#undef PAIR_STEP

    // Fused level 9 + leaf: one 16B gather + one LDS read finishes each tree.
    float leaf[kChains];
    {
        int4 rec[kChains];
#pragma unroll
        for (int c = 0; c < kChains; ++c) rec[c] = FU[p[c]];
#pragma unroll
        for (int c = 0; c < kChains; ++c) {
            leaf[c] = __int_as_float(
                xrow[rec[c].x] <= __int_as_float(rec[c].y) ? rec[c].w
                                                           : rec[c].z);
        }
    }

    // xs is dead now; reuse it as the output staging buffer.
    __syncthreads();
#pragma unroll
    for (int c = 0; c < kChains; ++c)
        outs[r * kOPad + tt + 32 * c] = leaf[c];
    __syncthreads();

#pragma unroll
    for (int k = 0; k < 4; ++k) {
        int j    = tid + k * kThreads;  // 0..2047
        int orow = j >> 7;              // 0..15
        int ocol = j & 127;             // 0..127
        __builtin_nontemporal_store(outs[orow * kOPad + ocol],
                                    &out[(size_t)(b0 + orow) * kT + t0 + ocol]);
    }
}

// Fallback (no workspace): straightforward per-level walk.
__global__ __launch_bounds__(512)
void traverse_plain_kernel(const float* __restrict__ x,
                           const int* __restrict__ root_nodes,
                           const float* __restrict__ root_biases,
                           const int* __restrict__ nodes,
                           const float* __restrict__ biases,
                           const float* __restrict__ leaf_nodes,
                           float* __restrict__ out)
{
    __shared__ float xs[16][kXPad];
    __shared__ float outs[16][65];

    const int b0  = blockIdx.x * 16;
    const int t0  = blockIdx.y * 64;
    const int tid = threadIdx.x;

    {
        const float4* xg = reinterpret_cast<const float4*>(x + (size_t)b0 * kF);
#pragma unroll
        for (int k = 0; k < 4; ++k) {
            int j = tid + k * 512;
            int r = j >> 7;
            int c = j & 127;
            float4 v = xg[(size_t)r * (kF / 4) + c];
            *reinterpret_cast<float4*>(&xs[r][c * 4]) = v;
        }
    }
    __syncthreads();

    const int r  = tid & 15;
    const int tt = tid >> 4;
    const int tA = t0 + tt;
    const int tB = t0 + tt + 32;
    const float* __restrict__ xrow = xs[r];

    int pA = 2 * tA + (xrow[root_nodes[tA]] <= root_biases[tA] ? 1 : 0);
    int pB = 2 * tB + (xrow[root_nodes[tB]] <= root_biases[tB] ? 1 : 0);

#pragma unroll
    for (int i = 1; i < kD; ++i) {
        const int*   ln = nodes  + (size_t)(i - 1) * kLvlPad;
        const float* lb = biases + (size_t)(i - 1) * kLvlPad;
        int   nA = ln[pA], nB = ln[pB];
        float bA = lb[pA], bB = lb[pB];
        pA = 2 * pA + (xrow[nA] <= bA ? 1 : 0);
        pB = 2 * pB + (xrow[nB] <= bB ? 1 : 0);
    }

    outs[r][tt]      = leaf_nodes[pA];
    outs[r][tt + 32] = leaf_nodes[pB];
    __syncthreads();

#pragma unroll
    for (int k = 0; k < 2; ++k) {
        int j    = tid + k * 512;
        int orow = j >> 6;
        int ocol = j & 63;
        __builtin_nontemporal_store(outs[orow][ocol],
                                    &out[(size_t)(b0 + orow) * kT + t0 + ocol]);
    }
}

extern "C" void kernel_launch(void* const* d_in, const int* in_sizes, int n_in,
                              void* d_out, int out_size, void* d_ws, size_t ws_size,
                              hipStream_t stream) {
    const float* x           = (const float*)d_in[0];
    const int*   root_nodes  = (const int*)d_in[1];
    const float* root_biases = (const float*)d_in[2];
    const int*   nodes       = (const int*)d_in[3];
    const float* biases      = (const float*)d_in[4];
    const float* leaf_nodes  = (const float*)d_in[5];
    float*       out         = (float*)d_out;

    if (ws_size >= kWsBytes) {
        prep_kernel<<<(kTotalRecs + 255) / 256, 256, 0, stream>>>(
            nodes, biases, leaf_nodes, (int4*)d_ws);
        const int nblocks = (kB / kRows) * (kT / kTrees); // 2048 * 2 = 4096
        traverse_pair_kernel<<<nblocks, kThreads, 0, stream>>>(
            x, root_nodes, root_biases, (const int4*)d_ws, out);
    } else {
        dim3 grid(kB / 16, kT / 64); // (2048, 4)
        traverse_plain_kernel<<<grid, 512, 0, stream>>>(
            x, root_nodes, root_biases, nodes, biases, leaf_nodes, out);
    }
}

// Round 12
// 59.739 us; speedup vs baseline: 1.2378x; 1.1279x over previous
//
#include <hip/hip_runtime.h>

// Problem constants (from the reference):
//   B=32768 batch, T=256 trees, D=10 depth, F=512 features, C=1 leaf dim
constexpr int kB = 32768;
constexpr int kT = 256;
constexpr int kD = 10;
constexpr int kF = 512;
constexpr int kLvlPad = kT << (kD - 1); // 131072
constexpr int kLevels = kD - 1;         // 9

constexpr int kRows    = 32;             // batch rows per block (32 lanes/tree)
constexpr int kTrees   = 128;            // trees per block (4 chains per thread)
constexpr int kChains  = 4;
constexpr int kThreads = 1024;           // 32 rows x 32 tree-slots
constexpr int kXPad    = 516;            // padded x row stride (floats)
constexpr int kOPad    = kTrees + 1;     // outs stride 129

// Pair-table record counts / offsets (16B records in d_ws).
// Pair (i,i+1) table indexed by the GLOBAL level-i index (width T*2^i):
//   {u32 n_top|nL<<9|nR<<18, f32 b_top, f32 bL, f32 bR}  (node idx < 512)
// One dwordx4 gather advances TWO levels. Fused record (level 9 + leaf):
//   {n9, b9, leaf[2j], leaf[2j+1]} indexed by global level-9 index.
constexpr int kP1 = kT * 2;      // 512
constexpr int kP3 = kT * 8;      // 2048
constexpr int kP5 = kT * 32;     // 8192
constexpr int kP7 = kT * 128;    // 32768
constexpr int kFU = kT * 512;    // 131072
constexpr int kO1 = 0;
constexpr int kO3 = kO1 + kP1;   // 512
constexpr int kO5 = kO3 + kP3;   // 2048+512 = 2560
constexpr int kO7 = kO5 + kP5;   // 10752
constexpr int kOF = kO7 + kP7;   // 43520
constexpr int kTotalRecs = kOF + kFU; // 174592
constexpr size_t kWsBytes = (size_t)kTotalRecs * 16; // 2,793,472 B

// Build all pair tables + fused table in one launch.
__global__ __launch_bounds__(256)
void prep_kernel(const int* __restrict__ nodes, const float* __restrict__ biases,
                 const float* __restrict__ leaf_nodes, int4* __restrict__ ws)
{
    int idx = blockIdx.x * 256 + threadIdx.x;
    if (idx < kOF) {
        int i, base;
        if      (idx < kO3) { i = 1; base = kO1; }
        else if (idx < kO5) { i = 3; base = kO3; }
        else if (idx < kO7) { i = 5; base = kO5; }
        else                { i = 7; base = kO7; }
        int j = idx - base;                      // global index into level i
        const int*   nt = nodes  + (size_t)(i - 1) * kLvlPad; // level i
        const float* bt = biases + (size_t)(i - 1) * kLvlPad;
        const int*   nc = nodes  + (size_t)i * kLvlPad;       // level i+1
        const float* bc = biases + (size_t)i * kLvlPad;
        unsigned int pk = (unsigned int)nt[j]
                        | ((unsigned int)nc[2 * j]     << 9)
                        | ((unsigned int)nc[2 * j + 1] << 18);
        ws[idx] = make_int4((int)pk, __float_as_int(bt[j]),
                            __float_as_int(bc[2 * j]),
                            __float_as_int(bc[2 * j + 1]));
    } else if (idx < kTotalRecs) {
        int j = idx - kOF;                       // global index into level 9
        const int   n9 = nodes [(size_t)(kD - 2) * kLvlPad + j];
        const float b9 = biases[(size_t)(kD - 2) * kLvlPad + j];
        ws[idx] = make_int4(n9, __float_as_int(b9),
                            __float_as_int(leaf_nodes[2 * j]),
                            __float_as_int(leaf_nodes[2 * j + 1]));
    }
}

// R8 structure with ONE change: 32 batch rows per block (32 lanes share each
// tree) instead of 16. Per-chain distinct-line cost at the deep levels drops
// 2.36 -> 1.84 (more draws per tree window per gather instruction), while
// LDS stays 66KB -> 2 blocks/CU -> 32 waves/CU (100% occupancy) — the
// combination R9 failed to achieve (its 64-row shape halved occupancy).
// Block = 32 rows x 128 trees, 1024 threads, 4 independent chains/thread.
// Chain: root -> 4 pair-steps -> fused = 6 dependent gathers. xs reused as
// output staging. Grid swizzled so the 2 tree-tiles of one x-tile sit 8
// dispatch slots apart (same XCD under round-robin).
__global__ __launch_bounds__(kThreads)
void traverse_pair_kernel(const float* __restrict__ x,
                          const int* __restrict__ root_nodes,
                          const float* __restrict__ root_biases,
                          const int4* __restrict__ ws,
                          float* __restrict__ out)
{
    __shared__ float xs[kRows][kXPad];        // 66,048 B (reused for outs)
    float* outs = &xs[0][0];                  // alias: [kRows][kOPad]

    const int bid = blockIdx.x;
    const int w   = bid >> 4;        // 16-block window
    const int s   = bid & 15;
    const int bx  = w * 8 + (s & 7); // x-tile, [0, 1024)
    const int by  = s >> 3;          // tree tile, [0, 2)
    const int b0  = bx * kRows;
    const int t0  = by * kTrees;
    const int tid = threadIdx.x;

    // Stage 32 x rows (4096 float4), coalesced.
    {
        const float4* xg = reinterpret_cast<const float4*>(x + (size_t)b0 * kF);
#pragma unroll
        for (int k = 0; k < 4; ++k) {
            int j = tid + k * kThreads;   // 0..4095
            int r = j >> 7;
            int c = j & 127;
            float4 v = xg[(size_t)r * (kF / 4) + c];
            *reinterpret_cast<float4*>(&xs[r][c * 4]) = v;
        }
    }
    __syncthreads();

    const int r  = tid & (kRows - 1); // row within tile (= lane&31)
    const int tt = tid >> 5;          // 0..31 (tree slot)
    const float* __restrict__ xrow = xs[r];

    int p[kChains];
#pragma unroll
    for (int c = 0; c < kChains; ++c) {
        int t = t0 + tt + 32 * c;
        p[c] = 2 * t + (xrow[root_nodes[t]] <= root_biases[t] ? 1 : 0);
    }

    const int4* __restrict__ P1 = ws + kO1;
    const int4* __restrict__ P3 = ws + kO3;
    const int4* __restrict__ P5 = ws + kO5;
    const int4* __restrict__ P7 = ws + kO7;
    const int4* __restrict__ FU = ws + kOF;

    // Pair step: one 16B gather advances two levels (R8's proven form).
#define PAIR_STEP(TBL)                                                        \
    {                                                                         \
        int4 rec[kChains];                                                    \
        _Pragma("unroll")                                                     \
        for (int c = 0; c < kChains; ++c) rec[c] = TBL[p[c]];                 \
        _Pragma("unroll")                                                     \
        for (int c = 0; c < kChains; ++c) {                                   \
            unsigned int n = (unsigned int)rec[c].x;                          \
            int c0 = xrow[n & 511u] <= __int_as_float(rec[c].y) ? 1 : 0;      \
            int nc = c0 ? (int)((n >> 18) & 511u) : (int)((n >> 9) & 511u);   \
            int bb = c0 ? rec[c].w : rec[c].z;                                \
            int c1 = xrow[nc] <= __int_as_float(bb) ? 1 : 0;                  \
            p[c] = 4 * p[c] + 2 * c0 + c1;                                    \
        }                                                                     \
    }

    PAIR_STEP(P1)   // levels 1,2
    PAIR_STEP(P3)   // levels 3,4
    PAIR_STEP(P5)   // levels 5,6
    PAIR_STEP(P7)   // levels 7,8
#undef PAIR_STEP

    // Fused level 9 + leaf: one 16B gather finishes each tree.
    float leaf[kChains];
    {
        int4 rec[kChains];
#pragma unroll
        for (int c = 0; c < kChains; ++c) rec[c] = FU[p[c]];
#pragma unroll
        for (int c = 0; c < kChains; ++c) {
            leaf[c] = __int_as_float(
                xrow[rec[c].x] <= __int_as_float(rec[c].y) ? rec[c].w
                                                           : rec[c].z);
        }
    }

    // xs is dead now; reuse it as the output staging buffer.
    __syncthreads();
#pragma unroll
    for (int c = 0; c < kChains; ++c)
        outs[r * kOPad + tt + 32 * c] = leaf[c];
    __syncthreads();

#pragma unroll
    for (int k = 0; k < 4; ++k) {
        int j    = tid + k * kThreads;  // 0..4095
        int orow = j >> 7;              // 0..31
        int ocol = j & 127;             // 0..127
        __builtin_nontemporal_store(outs[orow * kOPad + ocol],
                                    &out[(size_t)(b0 + orow) * kT + t0 + ocol]);
    }
}

// Fallback (no workspace): straightforward per-level walk.
__global__ __launch_bounds__(512)
void traverse_plain_kernel(const float* __restrict__ x,
                           const int* __restrict__ root_nodes,
                           const float* __restrict__ root_biases,
                           const int* __restrict__ nodes,
                           const float* __restrict__ biases,
                           const float* __restrict__ leaf_nodes,
                           float* __restrict__ out)
{
    __shared__ float xs[16][kXPad];
    __shared__ float outs[16][65];

    const int b0  = blockIdx.x * 16;
    const int t0  = blockIdx.y * 64;
    const int tid = threadIdx.x;

    {
        const float4* xg = reinterpret_cast<const float4*>(x + (size_t)b0 * kF);
#pragma unroll
        for (int k = 0; k < 4; ++k) {
            int j = tid + k * 512;
            int r = j >> 7;
            int c = j & 127;
            float4 v = xg[(size_t)r * (kF / 4) + c];
            *reinterpret_cast<float4*>(&xs[r][c * 4]) = v;
        }
    }
    __syncthreads();

    const int r  = tid & 15;
    const int tt = tid >> 4;
    const int tA = t0 + tt;
    const int tB = t0 + tt + 32;
    const float* __restrict__ xrow = xs[r];

    int pA = 2 * tA + (xrow[root_nodes[tA]] <= root_biases[tA] ? 1 : 0);
    int pB = 2 * tB + (xrow[root_nodes[tB]] <= root_biases[tB] ? 1 : 0);

#pragma unroll
    for (int i = 1; i < kD; ++i) {
        const int*   ln = nodes  + (size_t)(i - 1) * kLvlPad;
        const float* lb = biases + (size_t)(i - 1) * kLvlPad;
        int   nA = ln[pA], nB = ln[pB];
        float bA = lb[pA], bB = lb[pB];
        pA = 2 * pA + (xrow[nA] <= bA ? 1 : 0);
        pB = 2 * pB + (xrow[nB] <= bB ? 1 : 0);
    }

    outs[r][tt]      = leaf_nodes[pA];
    outs[r][tt + 32] = leaf_nodes[pB];
    __syncthreads();

#pragma unroll
    for (int k = 0; k < 2; ++k) {
        int j    = tid + k * 512;
        int orow = j >> 6;
        int ocol = j & 63;
        __builtin_nontemporal_store(outs[orow][ocol],
                                    &out[(size_t)(b0 + orow) * kT + t0 + ocol]);
    }
}

extern "C" void kernel_launch(void* const* d_in, const int* in_sizes, int n_in,
                              void* d_out, int out_size, void* d_ws, size_t ws_size,
                              hipStream_t stream) {
    const float* x           = (const float*)d_in[0];
    const int*   root_nodes  = (const int*)d_in[1];
    const float* root_biases = (const float*)d_in[2];
    const int*   nodes       = (const int*)d_in[3];
    const float* biases      = (const float*)d_in[4];
    const float* leaf_nodes  = (const float*)d_in[5];
    float*       out         = (float*)d_out;

    if (ws_size >= kWsBytes) {
        prep_kernel<<<(kTotalRecs + 255) / 256, 256, 0, stream>>>(
            nodes, biases, leaf_nodes, (int4*)d_ws);
        const int nblocks = (kB / kRows) * (kT / kTrees); // 1024 * 2 = 2048
        traverse_pair_kernel<<<nblocks, kThreads, 0, stream>>>(
            x, root_nodes, root_biases, (const int4*)d_ws, out);
    } else {
        dim3 grid(kB / 16, kT / 64); // (2048, 4)
        traverse_plain_kernel<<<grid, 512, 0, stream>>>(
            x, root_nodes, root_biases, nodes, biases, leaf_nodes, out);
    }
}